// Round 1
// baseline (781.026 us; speedup 1.0000x reference)
//
#include <hip/hip_runtime.h>

#define DEV __device__ __forceinline__

typedef __attribute__((ext_vector_type(8))) short bf16x8;
typedef __attribute__((ext_vector_type(4))) short s16x4;
typedef __attribute__((ext_vector_type(4))) float f32x4;

constexpr int Dd   = 64;
constexpr int Hh   = 128;
constexpr int Tt   = 1024;
constexpr int TLr  = 1022;   // T - L
constexpr int ROWS = 64;     // rows per workgroup
constexpr int NTHR = 512;    // 8 waves

#define MFMA16(a,b,c) __builtin_amdgcn_mfma_f32_16x16x32_bf16((a),(b),(c),0,0,0)

DEV short bf16hi(float f){
  unsigned u = __builtin_bit_cast(unsigned, f);
  u += 0x7FFFu + ((u >> 16) & 1u);          // round-to-nearest-even
  return (short)(u >> 16);
}
DEV float bf2f(short h){
  unsigned u = ((unsigned)(unsigned short)h) << 16;
  return __builtin_bit_cast(float, u);
}
DEV void splitbf(float f, short &h, short &l){
  h = bf16hi(f);
  l = bf16hi(f - bf2f(h));
}

// ACT: 0 none, 1 tanh, 2 relu, 3 leaky(0.2)
template<int A> DEV float actf(float x){
  if constexpr (A == 1){
    float e = __expf(2.f * x);                       // robust: e=inf -> 1, e=0 -> -1
    return 1.f - 2.f * __builtin_amdgcn_rcpf(e + 1.f);
  } else if constexpr (A == 2){
    return fmaxf(x, 0.f);
  } else if constexpr (A == 3){
    return x >= 0.f ? x : 0.2f * x;
  }
  return x;
}

// Stage W[HO][HI] (f32, row-major, k-contiguous) into LDS as swizzled bf16 hi/lo.
template<int HI, int HO>
DEV void stageW(const float* __restrict__ W, char* Wh, char* Wl, int tid){
  constexpr int rowB   = HI * 2;
  constexpr int total4 = HI * HO / 4;
  #pragma unroll
  for (int e4 = 0; e4 < total4 / NTHR; ++e4){
    int e    = (e4 * NTHR + tid) * 4;
    int feat = e >> (HI == 64 ? 6 : 7);
    int k    = e & (HI - 1);
    f32x4 v  = *(const f32x4*)(W + e);
    s16x4 hv, lv;
    #pragma unroll
    for (int j = 0; j < 4; ++j){
      short h, l; splitbf(v[j], h, l);
      hv[j] = h; lv[j] = l;
    }
    int byte = (feat * rowB + k * 2) ^ ((feat & 7) << 4);
    *(s16x4*)(Wh + byte) = hv;
    *(s16x4*)(Wl + byte) = lv;
  }
}

// One layer: C^T = W(HOxHI) . Act^T, over 64 rows shared by all 8 waves.
// Waves split output-feature tiles (and row-halves). Split-bf16 3-MFMA emulation.
template<int HI, int HO, int ACT, bool WOUT>
DEV void layerT(const char* aInH, const char* aInL, char* aOutH, char* aOutL,
                const char* WhB, const char* WlB, const float* __restrict__ bias,
                int w, int r16, int hi4, int ntBase, f32x4* out2)
{
  constexpr int NKT = HI / 32;
  constexpr int NMT = (HO == 128) ? 2 : 1;
  const int mtBase = (HO == 128) ? ((w & 3) * 2) : (w & 3);
  f32x4 acc[NMT][2];
  #pragma unroll
  for (int m = 0; m < NMT; ++m)
    #pragma unroll
    for (int i = 0; i < 2; ++i)
      acc[m][i] = (f32x4){0.f, 0.f, 0.f, 0.f};

  #pragma unroll
  for (int kt = 0; kt < NKT; ++kt){
    const int kOff = (kt * 32 + hi4 * 8) * 2;
    bf16x8 Bh[2], Bl[2];
    #pragma unroll
    for (int i = 0; i < 2; ++i){
      int rr = (ntBase + i) * 16 + r16;
      int byteB = (rr * 256 + kOff) ^ ((rr & 7) << 4);
      Bh[i] = *(const bf16x8*)(aInH + byteB);
      Bl[i] = *(const bf16x8*)(aInL + byteB);
    }
    #pragma unroll
    for (int m = 0; m < NMT; ++m){
      int feat  = (mtBase + m) * 16 + r16;
      int byteA = (feat * (HI * 2) + kOff) ^ ((feat & 7) << 4);
      bf16x8 Ah = *(const bf16x8*)(WhB + byteA);
      bf16x8 Al = *(const bf16x8*)(WlB + byteA);
      #pragma unroll
      for (int i = 0; i < 2; ++i){
        acc[m][i] = MFMA16(Ah, Bh[i], acc[m][i]);
        acc[m][i] = MFMA16(Ah, Bl[i], acc[m][i]);
        acc[m][i] = MFMA16(Al, Bh[i], acc[m][i]);
      }
    }
  }

  #pragma unroll
  for (int m = 0; m < NMT; ++m){
    int fB = (mtBase + m) * 16 + hi4 * 4;
    f32x4 bv = *(const f32x4*)(bias + fB);
    #pragma unroll
    for (int i = 0; i < 2; ++i){
      f32x4 v;
      #pragma unroll
      for (int j = 0; j < 4; ++j)
        v[j] = actf<ACT>(acc[m][i][j] + bv[j]);
      if constexpr (WOUT){
        int rr = (ntBase + i) * 16 + r16;
        s16x4 hv, lv;
        #pragma unroll
        for (int j = 0; j < 4; ++j){ short h, l; splitbf(v[j], h, l); hv[j] = h; lv[j] = l; }
        int byte = (rr * 256 + fB * 2) ^ ((rr & 7) << 4);
        *(s16x4*)(aOutH + byte) = hv;
        *(s16x4*)(aOutL + byte) = lv;
      } else {
        out2[i] = v;
      }
    }
  }
}

// Rebuild masked coupling input mx = u*m into activation buffer (features 0..63).
DEV void buildMx(char* aH, char* aL, const f32x4 u2[2], int keepBit,
                 int ntBase, int r16, int hi4, int fBaseS){
  #pragma unroll
  for (int i = 0; i < 2; ++i){
    int rr = (ntBase + i) * 16 + r16;
    s16x4 hv, lv;
    #pragma unroll
    for (int j = 0; j < 4; ++j){
      float v = ((j & 1) == keepBit) ? u2[i][j] : 0.f;  // f parity == j parity (fBaseS even)
      short h, l; splitbf(v, h, l); hv[j] = h; lv[j] = l;
    }
    int byte = (rr * 256 + fBaseS * 2) ^ ((rr & 7) << 4);
    *(s16x4*)(aH + byte) = hv;
    *(s16x4*)(aL + byte) = lv;
  }
}

// Build f1 sliding-window input: win[r] = concat(x[t0+r], x[t0+r+1]) (128 features).
DEV void buildWin(char* aH, char* aL, const float* __restrict__ xb, int t0, int tid){
  int rr = tid >> 3;
  int fg = (tid & 7) << 4;                 // feature group of 16
  int xr = t0 + rr + (fg >= 64 ? 1 : 0);
  if (xr > Tt - 1) xr = Tt - 1;            // clamp (rows past TL are discarded)
  int fo = fg & 63;
  const f32x4* p = (const f32x4*)(xb + xr * Dd + fo);
  int swz   = (rr & 7) << 4;
  int byte0 = rr * 256 + fg * 2;
  #pragma unroll
  for (int half = 0; half < 2; ++half){
    f32x4 a = p[half * 2], b = p[half * 2 + 1];
    bf16x8 h8, l8;
    #pragma unroll
    for (int j = 0; j < 4; ++j){
      short h, l;
      splitbf(a[j], h, l); h8[j] = h;     l8[j] = l;
      splitbf(b[j], h, l); h8[4 + j] = h; l8[4 + j] = l;
    }
    int byte = (byte0 + half * 16) ^ swz;
    *(bf16x8*)(aH + byte) = h8;
    *(bf16x8*)(aL + byte) = l8;
  }
}

__global__ __launch_bounds__(NTHR, 2)
void pnl_main(const float* __restrict__ x,
              const float* __restrict__ f1_hW, const float* __restrict__ f1_hb,
              const float* __restrict__ f1_oW, const float* __restrict__ f1_ob,
              const float* __restrict__ sW0, const float* __restrict__ sb0,
              const float* __restrict__ sW1, const float* __restrict__ sb1,
              const float* __restrict__ sW2, const float* __restrict__ sb2,
              const float* __restrict__ tW0, const float* __restrict__ tb0,
              const float* __restrict__ tW1, const float* __restrict__ tb1,
              const float* __restrict__ tW2, const float* __restrict__ tb2,
              float* __restrict__ resid, float* __restrict__ wsPart)
{
  __shared__ __align__(16) char Wh[32768];
  __shared__ __align__(16) char Wl[32768];
  __shared__ __align__(16) char aH[2][16384];
  __shared__ __align__(16) char aL[2][16384];
  __shared__ float ldetS[ROWS];

  const int tid   = threadIdx.x;
  const int w     = tid >> 6;
  const int lane  = tid & 63;
  const int r16   = lane & 15;
  const int hi4   = lane >> 4;
  const int bIdx  = blockIdx.x >> 4;
  const int t0    = (blockIdx.x & 15) * ROWS;
  const int ntBase = (w >> 2) * 2;
  const int fBaseS = (w & 3) * 16 + hi4 * 4;   // small-layer (Ho=64) feature base

  if (tid < ROWS) ldetS[tid] = 0.f;

  const float* xb = x + (long)bIdx * Tt * Dd;

  // u init = x[b, t0+2+rr, :]  (flow input), kept in registers in C-frag layout
  f32x4 u2[2];
  #pragma unroll
  for (int i = 0; i < 2; ++i){
    int rr = (ntBase + i) * 16 + r16;
    int xr = t0 + 2 + rr; if (xr > Tt - 1) xr = Tt - 1;
    u2[i] = *(const f32x4*)(xb + xr * Dd + fBaseS);
  }
  float ld0 = 0.f, ld1 = 0.f;
  f32x4 sA[2], tA[2];

  for (int blk = 0; blk < 3; ++blk){
    const int keepBit = 1 - (blk & 1);   // blk0/2 keep odd features, blk1 keeps even

    buildMx(aH[0], aL[0], u2, keepBit, ntBase, r16, hi4, fBaseS);
    stageW<64,128>(sW0 + blk * Hh * Dd, Wh, Wl, tid);
    __syncthreads();
    layerT<64,128,1,true >(aH[0],aL[0], aH[1],aL[1], Wh,Wl, sb0 + blk*Hh, w,r16,hi4,ntBase, nullptr);
    __syncthreads();
    stageW<128,128>(sW1 + blk * Hh * Hh, Wh, Wl, tid);
    __syncthreads();
    layerT<128,128,1,true >(aH[1],aL[1], aH[0],aL[0], Wh,Wl, sb1 + blk*Hh, w,r16,hi4,ntBase, nullptr);
    __syncthreads();
    stageW<128,64>(sW2 + blk * Dd * Hh, Wh, Wl, tid);
    __syncthreads();
    layerT<128,64,0,false>(aH[0],aL[0], nullptr,nullptr, Wh,Wl, sb2 + blk*Dd, w,r16,hi4,ntBase, sA);
    __syncthreads();

    buildMx(aH[0], aL[0], u2, keepBit, ntBase, r16, hi4, fBaseS);
    stageW<64,128>(tW0 + blk * Hh * Dd, Wh, Wl, tid);
    __syncthreads();
    layerT<64,128,2,true >(aH[0],aL[0], aH[1],aL[1], Wh,Wl, tb0 + blk*Hh, w,r16,hi4,ntBase, nullptr);
    __syncthreads();
    stageW<128,128>(tW1 + blk * Hh * Hh, Wh, Wl, tid);
    __syncthreads();
    layerT<128,128,2,true >(aH[1],aL[1], aH[0],aL[0], Wh,Wl, tb1 + blk*Hh, w,r16,hi4,ntBase, nullptr);
    __syncthreads();
    stageW<128,64>(tW2 + blk * Dd * Hh, Wh, Wl, tid);
    __syncthreads();
    layerT<128,64,0,false>(aH[0],aL[0], nullptr,nullptr, Wh,Wl, tb2 + blk*Dd, w,r16,hi4,ntBase, tA);
    __syncthreads();

    // coupling update (registers only): updated features have parity != keepBit
    #pragma unroll
    for (int i = 0; i < 2; ++i){
      #pragma unroll
      for (int j = 0; j < 4; ++j){
        if ((j & 1) != keepBit){
          float e = __expf(-sA[i][j]);
          u2[i][j] = (u2[i][j] - tA[i][j]) * e;
          if (i == 0) ld0 -= sA[i][j]; else ld1 -= sA[i][j];
        }
      }
    }
  }

  // f1 sliding-window MLP
  buildWin(aH[0], aL[0], xb, t0, tid);
  stageW<128,128>(f1_hW, Wh, Wl, tid);
  __syncthreads();
  layerT<128,128,3,true >(aH[0],aL[0], aH[1],aL[1], Wh,Wl, f1_hb, w,r16,hi4,ntBase, nullptr);
  __syncthreads();
  stageW<128,128>(f1_hW + Hh*Hh, Wh, Wl, tid);
  __syncthreads();
  layerT<128,128,3,true >(aH[1],aL[1], aH[0],aL[0], Wh,Wl, f1_hb + Hh, w,r16,hi4,ntBase, nullptr);
  __syncthreads();
  stageW<128,128>(f1_hW + 2*Hh*Hh, Wh, Wl, tid);
  __syncthreads();
  layerT<128,128,3,true >(aH[0],aL[0], aH[1],aL[1], Wh,Wl, f1_hb + 2*Hh, w,r16,hi4,ntBase, nullptr);
  __syncthreads();
  stageW<128,64>(f1_oW, Wh, Wl, tid);
  __syncthreads();
  f32x4 oA[2];
  layerT<128,64,0,false>(aH[1],aL[1], nullptr,nullptr, Wh,Wl, f1_ob, w,r16,hi4,ntBase, oA);

  // residuals = f1(win) - x_inv  (x_inv == u2, same fragment layout)
  #pragma unroll
  for (int i = 0; i < 2; ++i){
    int rr  = (ntBase + i) * 16 + r16;
    int tau = t0 + rr;
    if (tau < TLr){
      f32x4 st;
      #pragma unroll
      for (int j = 0; j < 4; ++j) st[j] = oA[i][j] - u2[i][j];
      *(f32x4*)(resid + ((long)(bIdx * TLr + tau)) * Dd + fBaseS) = st;
    }
  }

  // logdet: reduce per-lane partials over the 4 k-group lanes, then across waves via LDS
  float v0 = ld0; v0 += __shfl_xor(v0, 16); v0 += __shfl_xor(v0, 32);
  float v1 = ld1; v1 += __shfl_xor(v1, 16); v1 += __shfl_xor(v1, 32);
  if (hi4 == 0){
    atomicAdd(&ldetS[ ntBase      * 16 + r16], v0);
    atomicAdd(&ldetS[(ntBase + 1) * 16 + r16], v1);
  }
  __syncthreads();
  if (w == 0){
    float v = (t0 + lane < TLr) ? ldetS[lane] : 0.f;
    #pragma unroll
    for (int off = 1; off < 64; off <<= 1) v += __shfl_xor(v, off);
    if (lane == 0) wsPart[blockIdx.x] = v;
  }
}

// Deterministic final reduce: 16 tile-partials per batch element.
__global__ void pnl_ldet(const float* __restrict__ ws, float* __restrict__ outLd){
  int b = threadIdx.x;
  float s = 0.f;
  #pragma unroll
  for (int t = 0; t < 16; ++t) s += ws[b * 16 + t];
  outLd[b] = s;
}

extern "C" void kernel_launch(void* const* d_in, const int* in_sizes, int n_in,
                              void* d_out, int out_size, void* d_ws, size_t ws_size,
                              hipStream_t stream){
  const float* x     = (const float*)d_in[0];
  const float* f1_hW = (const float*)d_in[1];
  const float* f1_hb = (const float*)d_in[2];
  const float* f1_oW = (const float*)d_in[3];
  const float* f1_ob = (const float*)d_in[4];
  const float* sW0   = (const float*)d_in[5];
  const float* sb0   = (const float*)d_in[6];
  const float* sW1   = (const float*)d_in[7];
  const float* sb1   = (const float*)d_in[8];
  const float* sW2   = (const float*)d_in[9];
  const float* sb2   = (const float*)d_in[10];
  const float* tW0   = (const float*)d_in[11];
  const float* tb0   = (const float*)d_in[12];
  const float* tW1   = (const float*)d_in[13];
  const float* tb1   = (const float*)d_in[14];
  const float* tW2   = (const float*)d_in[15];
  const float* tb2   = (const float*)d_in[16];

  float* resid = (float*)d_out;
  float* outLd = resid + (long)256 * TLr * Dd;
  float* wsP   = (float*)d_ws;

  pnl_main<<<dim3(256 * 16), dim3(NTHR), 0, stream>>>(
      x, f1_hW, f1_hb, f1_oW, f1_ob,
      sW0, sb0, sW1, sb1, sW2, sb2,
      tW0, tb0, tW1, tb1, tW2, tb2, resid, wsP);
  pnl_ldet<<<dim3(1), dim3(256), 0, stream>>>(wsP, outLd);
}